// Round 1
// baseline (4073.273 us; speedup 1.0000x reference)
//
#include <hip/hip_runtime.h>

// 3-layer LSTM, B=256, T=2048, H=32, in=64. fp32 throughout.
// One block per batch element (256 blocks), 128 threads = one per gate row.
// Weights per-thread in VGPRs; h state in LDS; input staged per 8-step chunk
// with register prefetch. Layers launched sequentially; layer1/2 run in-place
// on a single (B,T,32) h_seq buffer in d_ws (needs 64 MiB of ws).

constexpr int T_SEQ = 2048;
constexpr int HID   = 32;
constexpr int GATES = 128;
constexpr int CH    = 8;   // timesteps staged per LDS chunk

__device__ __forceinline__ float fast_sigmoid(float x) {
    return 1.0f / (1.0f + __expf(-x));
}
__device__ __forceinline__ float fast_tanh(float x) {
    // tanh(x) = 1 - 2/(exp(2x)+1); exact at +-inf, ~2ulp elsewhere
    return 1.0f - 2.0f / (__expf(2.0f * x) + 1.0f);
}

template<int IN_DIM, bool LAST>
__global__ __launch_bounds__(128)
void lstm_layer_kernel(const float* in,                     // (B, T, IN_DIM); may alias out
                       const float* __restrict__ W_ih,      // (128, IN_DIM)
                       const float* __restrict__ W_hh,      // (128, 32)
                       const float* __restrict__ bias,      // (128,)
                       float* out,                          // (B, T, 32) or (B,) if LAST
                       const float* __restrict__ W_out,     // (1, 32) if LAST
                       const float* __restrict__ b_out)     // (1,)    if LAST
{
    const int bi = blockIdx.x;
    const int g  = threadIdx.x;   // gate row 0..127

    // per-thread weight rows in registers
    float wih[IN_DIM];
#pragma unroll
    for (int d = 0; d < IN_DIM; ++d) wih[d] = W_ih[g * IN_DIM + d];
    float whh[HID];
#pragma unroll
    for (int k = 0; k < HID; ++k) whh[k] = W_hh[g * HID + k];
    const float bg = bias[g];

    __shared__ float h_lds[HID];
    __shared__ float gact[GATES];
    __shared__ float in_tile[CH * IN_DIM];

    if (g < HID) h_lds[g] = 0.0f;
    __syncthreads();

    float c = 0.0f;

    const float* src = in + (size_t)bi * T_SEQ * IN_DIM;
    constexpr int NV4 = CH * IN_DIM / 4;   // float4 loads per chunk (128 or 64)

    // prefetch chunk 0
    float4 pref = make_float4(0.f, 0.f, 0.f, 0.f);
    if (g < NV4) pref = reinterpret_cast<const float4*>(src)[g];

    const size_t out_base = (size_t)bi * T_SEQ * HID;

    for (int t = 0; t < T_SEQ; ++t) {
        const int tt = t & (CH - 1);
        if (tt == 0) {
            // all threads are past the end-of-step barrier of t-1 -> safe to overwrite
            if (g < NV4) reinterpret_cast<float4*>(in_tile)[g] = pref;
            __syncthreads();
            if (g < NV4 && t + CH < T_SEQ) {
                pref = reinterpret_cast<const float4*>(src + (size_t)(t + CH) * IN_DIM)[g];
            }
        }

        float acc = bg;
        const float* it = &in_tile[tt * IN_DIM];
#pragma unroll
        for (int d = 0; d < IN_DIM; ++d) acc = fmaf(it[d], wih[d], acc);
#pragma unroll
        for (int k = 0; k < HID; ++k) acc = fmaf(h_lds[k], whh[k], acc);

        // gate activation: rows 0-31 i(sig), 32-63 f(sig), 64-95 g(tanh), 96-127 o(sig)
        float a = (g >= 64 && g < 96) ? fast_tanh(acc) : fast_sigmoid(acc);
        gact[g] = a;
        __syncthreads();

        if (g < HID) {
            const float iv = gact[g];
            const float fv = gact[g + 32];
            const float gv = gact[g + 64];
            const float ov = gact[g + 96];
            c = fmaf(fv, c, iv * gv);
            const float h = ov * fast_tanh(c);
            h_lds[g] = h;
            if (!LAST) out[out_base + (size_t)t * HID + g] = h;
        }
        __syncthreads();
    }

    if (LAST) {
        if (g == 0) {
            float s = b_out[0];
#pragma unroll
            for (int j = 0; j < HID; ++j) s = fmaf(h_lds[j], W_out[j], s);
            out[bi] = s;   // (256,1) output
        }
    }
}

extern "C" void kernel_launch(void* const* d_in, const int* in_sizes, int n_in,
                              void* d_out, int out_size, void* d_ws, size_t ws_size,
                              hipStream_t stream) {
    const float* x      = (const float*)d_in[0];
    const float* W_ih0  = (const float*)d_in[1];
    const float* W_hh0  = (const float*)d_in[2];
    const float* b0     = (const float*)d_in[3];
    const float* W_ih1  = (const float*)d_in[4];
    const float* W_hh1  = (const float*)d_in[5];
    const float* b1     = (const float*)d_in[6];
    const float* W_ih2  = (const float*)d_in[7];
    const float* W_hh2  = (const float*)d_in[8];
    const float* b2     = (const float*)d_in[9];
    const float* W_out  = (const float*)d_in[10];
    const float* b_out  = (const float*)d_in[11];

    float* hseq = (float*)d_ws;   // (B, T, 32) fp32 = 64 MiB, reused in-place by L1/L2
    float* outp = (float*)d_out;  // (256,) fp32

    lstm_layer_kernel<64, false><<<256, 128, 0, stream>>>(x,    W_ih0, W_hh0, b0, hseq, nullptr, nullptr);
    lstm_layer_kernel<32, false><<<256, 128, 0, stream>>>(hseq, W_ih1, W_hh1, b1, hseq, nullptr, nullptr);
    lstm_layer_kernel<32, true ><<<256, 128, 0, stream>>>(hseq, W_ih2, W_hh2, b2, outp, W_out, b_out);
}

// Round 2
// 3553.439 us; speedup vs baseline: 1.1463x; 1.1463x over previous
//
#include <hip/hip_runtime.h>

// 3-layer LSTM, B=256, T=2048, H=32, in=64. fp32.
// One WAVE (64 lanes) per batch element, grid=256. Zero barriers:
//  - lane l owns gate rows l and l+64 (weights in VGPRs)
//  - gate exchange via __shfl_xor(.,32); h broadcast via wave-synchronous LDS
//  - x staged in LDS chunks via global_load_lds, double-buffered, counted vmcnt
//  - h_seq stores are fire-and-forget (no __syncthreads -> no vmcnt(0) drain)

constexpr int T_SEQ = 2048;
constexpr int HID   = 32;
constexpr int CH    = 16;   // timesteps per LDS chunk

__device__ __forceinline__ float sigmoid_f(float x) { return 1.0f / (1.0f + __expf(-x)); }
__device__ __forceinline__ float tanh_f(float x)    { return 1.0f - 2.0f / (__expf(2.0f * x) + 1.0f); }

#define GLOAD_LDS16(gsrc, ldst)                                                              \
    __builtin_amdgcn_global_load_lds((const __attribute__((address_space(1))) void*)(gsrc), \
                                     (__attribute__((address_space(3))) void*)(ldst),        \
                                     16, 0, 0)

template<int IN_DIM, bool LAST>
__global__ __launch_bounds__(64, 1)
void lstm_wave_kernel(const float* __restrict__ in,     // (B,T,IN_DIM); may alias out
                      const float* __restrict__ W_ih,   // (128, IN_DIM)
                      const float* __restrict__ W_hh,   // (128, 32)
                      const float* __restrict__ bias,   // (128,)
                      float* __restrict__ out,          // (B,T,32) or (B,) if LAST
                      const float* __restrict__ W_out,  // (1,32) if LAST
                      const float* __restrict__ b_out)  // (1,)   if LAST
{
    const int bi = blockIdx.x;
    const int l  = threadIdx.x;          // 0..63
    const int gA = l, gB = l + 64;

    // per-lane weight rows in registers (~192 VGPRs for layer 0)
    float wihA[IN_DIM], wihB[IN_DIM];
#pragma unroll
    for (int d = 0; d < IN_DIM; ++d) { wihA[d] = W_ih[gA*IN_DIM + d]; wihB[d] = W_ih[gB*IN_DIM + d]; }
    float whhA[HID], whhB[HID];
#pragma unroll
    for (int k = 0; k < HID; ++k)    { whhA[k] = W_hh[gA*HID + k]; whhB[k] = W_hh[gB*HID + k]; }
    const float bA = bias[gA], bB = bias[gB];

    __shared__ float xbuf[2][CH * IN_DIM];
    __shared__ float h_lds[HID];

    if (l < HID) h_lds[l] = 0.0f;
    asm volatile("s_waitcnt lgkmcnt(0)" ::: "memory");

    float c = 0.0f, hreg = 0.0f;
    const float* src = in + (size_t)bi * T_SEQ * IN_DIM;
    constexpr int NLOADS = CH * IN_DIM * 4 / 1024;   // 1 KiB per global_load_lds (64 lanes x 16B)

    // prologue: chunk 0 -> buf 0
#pragma unroll
    for (int i = 0; i < NLOADS; ++i)
        GLOAD_LDS16(src + i*256 + l*4, &xbuf[0][i*256 + l*4]);

    const size_t out_base = (size_t)bi * T_SEQ * HID;
    int cur = 0;

    for (int c0 = 0; c0 < T_SEQ; c0 += CH) {
        if (c0 + CH < T_SEQ) {
            const float* nsrc = src + (size_t)(c0 + CH) * IN_DIM;
#pragma unroll
            for (int i = 0; i < NLOADS; ++i)
                GLOAD_LDS16(nsrc + i*256 + l*4, &xbuf[cur ^ 1][i*256 + l*4]);
            // wait until only the NLOADS just-issued remain -> chunk `cur` is resident
            if constexpr (IN_DIM == 64) asm volatile("s_waitcnt vmcnt(4)" ::: "memory");
            else                        asm volatile("s_waitcnt vmcnt(2)" ::: "memory");
        } else {
            asm volatile("s_waitcnt vmcnt(0)" ::: "memory");
        }

#pragma unroll
        for (int tt = 0; tt < CH; ++tt) {
            // ---- x-dot (independent of h; compiler may hoist across step tail) ----
            const float4* xt = reinterpret_cast<const float4*>(&xbuf[cur][tt * IN_DIM]);
            float a0 = bA, a1 = 0.f, b0 = bB, b1 = 0.f;
#pragma unroll
            for (int d4 = 0; d4 < IN_DIM/4; ++d4) {
                const float4 xv = xt[d4];
                a0 = fmaf(xv.x, wihA[4*d4+0], a0);
                a1 = fmaf(xv.y, wihA[4*d4+1], a1);
                a0 = fmaf(xv.z, wihA[4*d4+2], a0);
                a1 = fmaf(xv.w, wihA[4*d4+3], a1);
                b0 = fmaf(xv.x, wihB[4*d4+0], b0);
                b1 = fmaf(xv.y, wihB[4*d4+1], b1);
                b0 = fmaf(xv.z, wihB[4*d4+2], b0);
                b1 = fmaf(xv.w, wihB[4*d4+3], b1);
            }
            // enforce: previous step's h_lds write is complete before we read it
            asm volatile("s_waitcnt lgkmcnt(0)" ::: "memory");
            const float4* hv4 = reinterpret_cast<const float4*>(h_lds);
#pragma unroll
            for (int k4 = 0; k4 < HID/4; ++k4) {
                const float4 hv = hv4[k4];
                a0 = fmaf(hv.x, whhA[4*k4+0], a0);
                a1 = fmaf(hv.y, whhA[4*k4+1], a1);
                a0 = fmaf(hv.z, whhA[4*k4+2], a0);
                a1 = fmaf(hv.w, whhA[4*k4+3], a1);
                b0 = fmaf(hv.x, whhB[4*k4+0], b0);
                b1 = fmaf(hv.y, whhB[4*k4+1], b1);
                b0 = fmaf(hv.z, whhB[4*k4+2], b0);
                b1 = fmaf(hv.w, whhB[4*k4+3], b1);
            }
            const float ga = a0 + a1, gb = b0 + b1;
            // gate rows: lane l<32 -> accA=i (sig), accB=g (tanh)
            //            lane l>=32 -> accA=f (sig), accB=o (sig, via tanh half-arg)
            const float sA = sigmoid_f(ga);
            const float tb = tanh_f(l < 32 ? gb : 0.5f * gb);
            const float aB = (l < 32) ? tb : fmaf(0.5f, tb, 0.5f);
            const float fv = __shfl_xor(sA, 32);   // lane j<32 gets f from lane j+32
            const float ov = __shfl_xor(aB, 32);   // lane j<32 gets o from lane j+32
            const float cn = fmaf(fv, c, sA * aB); // meaningful for lanes < 32
            const float hn = ov * tanh_f(cn);
            if (l < HID) {
                c = cn; hreg = hn;
                h_lds[l] = hn;
                if constexpr (!LAST) out[out_base + (size_t)(c0 + tt) * HID + l] = hn;
            }
        }
        cur ^= 1;
    }

    if constexpr (LAST) {
        float s = (l < HID) ? hreg * W_out[l] : 0.0f;
#pragma unroll
        for (int off = 16; off; off >>= 1) s += __shfl_xor(s, off);
        if (l == 0) out[bi] = s + b_out[0];
    }
}

extern "C" void kernel_launch(void* const* d_in, const int* in_sizes, int n_in,
                              void* d_out, int out_size, void* d_ws, size_t ws_size,
                              hipStream_t stream) {
    const float* x      = (const float*)d_in[0];
    const float* W_ih0  = (const float*)d_in[1];
    const float* W_hh0  = (const float*)d_in[2];
    const float* b0     = (const float*)d_in[3];
    const float* W_ih1  = (const float*)d_in[4];
    const float* W_hh1  = (const float*)d_in[5];
    const float* b1     = (const float*)d_in[6];
    const float* W_ih2  = (const float*)d_in[7];
    const float* W_hh2  = (const float*)d_in[8];
    const float* b2     = (const float*)d_in[9];
    const float* W_out  = (const float*)d_in[10];
    const float* b_out  = (const float*)d_in[11];

    float* hseq = (float*)d_ws;   // (B,T,32) fp32 = 64 MiB; reused in-place by layer 1
    float* outp = (float*)d_out;  // (256,) fp32

    lstm_wave_kernel<64, false><<<256, 64, 0, stream>>>(x,    W_ih0, W_hh0, b0, hseq, nullptr, nullptr);
    lstm_wave_kernel<32, false><<<256, 64, 0, stream>>>(hseq, W_ih1, W_hh1, b1, hseq, nullptr, nullptr);
    lstm_wave_kernel<32, true ><<<256, 64, 0, stream>>>(hseq, W_ih2, W_hh2, b2, outp, W_out, b_out);
}

// Round 3
// 1678.914 us; speedup vs baseline: 2.4261x; 2.1165x over previous
//
#include <hip/hip_runtime.h>

// 3-layer LSTM, B=256, T=2048, H=32, in=64. fp32.
// ONE kernel: 256 blocks (one per chain) x 192 threads (3 waves).
// Wave l runs layer l, software-pipelined by 16-step chunks:
//   phase p: wave0 computes chunk p, wave1 chunk p-1, wave2 chunk p-2.
// h-chunks hand off through double-buffered LDS rings; one __syncthreads
// per phase. h_seq never touches HBM; only the final 256-float projection
// is written. Weights live in VGPRs (amdgpu_waves_per_eu(1,1) to prevent
// the round-2 spill-to-scratch at VGPR=116).

constexpr int T_SEQ  = 2048;
constexpr int HID    = 32;
constexpr int CH     = 16;             // timesteps per chunk
constexpr int NCHUNK = T_SEQ / CH;     // 128
constexpr int NPHASE = NCHUNK + 2;     // pipeline depth 3

__device__ __forceinline__ float sigmoid_f(float x) { return 1.0f / (1.0f + __expf(-x)); }
__device__ __forceinline__ float tanh_f(float x)    { return 1.0f - 2.0f / (__expf(2.0f * x) + 1.0f); }

#define GLOAD_LDS16(gsrc, ldst)                                                              \
    __builtin_amdgcn_global_load_lds((const __attribute__((address_space(1))) void*)(gsrc), \
                                     (__attribute__((address_space(3))) void*)(ldst),        \
                                     16, 0, 0)

// dual-gate dot: acc{a,b} += x . w{A,B}, 2 chains per gate
template<int N4, int SZ>
__device__ __forceinline__ void dot4(const float4* xt,
                                     const float (&wA)[SZ], const float (&wB)[SZ],
                                     float& a0, float& a1, float& b0, float& b1)
{
#pragma unroll
    for (int i = 0; i < N4; ++i) {
        const float4 v = xt[i];
        a0 = fmaf(v.x, wA[4*i+0], a0); a1 = fmaf(v.y, wA[4*i+1], a1);
        a0 = fmaf(v.z, wA[4*i+2], a0); a1 = fmaf(v.w, wA[4*i+3], a1);
        b0 = fmaf(v.x, wB[4*i+0], b0); b1 = fmaf(v.y, wB[4*i+1], b1);
        b0 = fmaf(v.z, wB[4*i+2], b0); b1 = fmaf(v.w, wB[4*i+3], b1);
    }
}

// gate activations + state update. lane l<32: A=i, B=g ; lane>=32: A=f, B=o.
__device__ __forceinline__ void gate_tail(int l, float ga, float gb,
                                          float& c, float& hreg,
                                          float* hb_row, float* ring_row)
{
    const float sA = sigmoid_f(ga);
    const float tb = tanh_f(l < 32 ? gb : 0.5f * gb);
    const float aB = (l < 32) ? tb : fmaf(0.5f, tb, 0.5f);   // o via tanh half-arg
    const float fv = __shfl_xor(sA, 32);
    const float ov = __shfl_xor(aB, 32);
    const float cn = fmaf(fv, c, sA * aB);
    const float hn = ov * tanh_f(cn);
    if (l < HID) {
        c = cn; hreg = hn;
        hb_row[l] = hn;
        if (ring_row) ring_row[l] = hn;
    }
}

__global__ __launch_bounds__(192) __attribute__((amdgpu_waves_per_eu(1, 1)))
void lstm3_pipe_kernel(const float* __restrict__ x,
                       const float* __restrict__ W_ih0, const float* __restrict__ W_hh0, const float* __restrict__ b0,
                       const float* __restrict__ W_ih1, const float* __restrict__ W_hh1, const float* __restrict__ b1,
                       const float* __restrict__ W_ih2, const float* __restrict__ W_hh2, const float* __restrict__ b2,
                       const float* __restrict__ W_out, const float* __restrict__ b_out,
                       float* __restrict__ out)
{
    const int bi = blockIdx.x;
    const int w  = threadIdx.x >> 6;   // wave id = layer id
    const int l  = threadIdx.x & 63;

    __shared__ float xstage[2][CH * 64];     // layer-0 input staging (8 KB)
    __shared__ float ring0[2][CH][HID];      // h0 chunks: wave0 -> wave1 (4 KB)
    __shared__ float ring1[2][CH][HID];      // h1 chunks: wave1 -> wave2 (4 KB)
    __shared__ float hb[3][HID];             // per-wave h broadcast

    // ---- per-lane weights in VGPRs ----
    float wihA[64], wihB[64], whhA[32], whhB[32];
    float bA, bB, wout = 0.0f;

    if (w == 0) {
#pragma unroll
        for (int d = 0; d < 64; ++d) { wihA[d] = W_ih0[l*64 + d]; wihB[d] = W_ih0[(l+64)*64 + d]; }
#pragma unroll
        for (int k = 0; k < 32; ++k) { whhA[k] = W_hh0[l*32 + k]; whhB[k] = W_hh0[(l+64)*32 + k]; }
        bA = b0[l]; bB = b0[l + 64];
    } else {
        const float* Wih = (w == 1) ? W_ih1 : W_ih2;
        const float* Whh = (w == 1) ? W_hh1 : W_hh2;
        const float* bb  = (w == 1) ? b1    : b2;
#pragma unroll
        for (int d = 0; d < 32; ++d) { wihA[d] = Wih[l*32 + d]; wihB[d] = Wih[(l+64)*32 + d]; }
#pragma unroll
        for (int k = 0; k < 32; ++k) { whhA[k] = Whh[l*32 + k]; whhB[k] = Whh[(l+64)*32 + k]; }
        bA = bb[l]; bB = bb[l + 64];
        if (w == 2 && l < HID) wout = W_out[l];
    }

    if (l < HID) hb[w][l] = 0.0f;

    float c = 0.0f, hreg = 0.0f;
    const float* src = x + (size_t)bi * T_SEQ * 64;

    // prologue: stage chunk 0
    if (w == 0) {
#pragma unroll
        for (int i = 0; i < 4; ++i) GLOAD_LDS16(src + i*256 + l*4, &xstage[0][i*256 + l*4]);
    }
    __syncthreads();   // drains vmcnt -> chunk 0 resident; hb inits visible

    for (int p = 0; p < NPHASE; ++p) {
        if (w == 0) {
            if (p + 1 < NCHUNK) {   // prefetch next chunk; lands by this phase's barrier
                const float* ns = src + (size_t)(p + 1) * CH * 64;
                float* dst = &xstage[(p + 1) & 1][0];
#pragma unroll
                for (int i = 0; i < 4; ++i) GLOAD_LDS16(ns + i*256 + l*4, dst + i*256 + l*4);
            }
            if (p < NCHUNK) {
                const float* xs = &xstage[p & 1][0];
                float (*rout)[HID] = ring0[p & 1];
#pragma unroll
                for (int tt = 0; tt < CH; ++tt) {
                    float a0 = bA, a1 = 0.f, g0 = bB, g1 = 0.f;
                    dot4<16>(reinterpret_cast<const float4*>(xs + tt*64), wihA, wihB, a0, a1, g0, g1);
                    asm volatile("s_waitcnt lgkmcnt(0)" ::: "memory");   // prev step's hb write done
                    dot4<8>(reinterpret_cast<const float4*>(hb[0]), whhA, whhB, a0, a1, g0, g1);
                    gate_tail(l, a0 + a1, g0 + g1, c, hreg, hb[0], rout[tt]);
                }
            }
        } else if (w == 1) {
            const int ci = p - 1;
            if (ci >= 0 && ci < NCHUNK) {
                const float (*rin)[HID] = ring0[ci & 1];
                float (*rout)[HID] = ring1[ci & 1];
#pragma unroll
                for (int tt = 0; tt < CH; ++tt) {
                    float a0 = bA, a1 = 0.f, g0 = bB, g1 = 0.f;
                    dot4<8>(reinterpret_cast<const float4*>(rin[tt]), wihA, wihB, a0, a1, g0, g1);
                    asm volatile("s_waitcnt lgkmcnt(0)" ::: "memory");
                    dot4<8>(reinterpret_cast<const float4*>(hb[1]), whhA, whhB, a0, a1, g0, g1);
                    gate_tail(l, a0 + a1, g0 + g1, c, hreg, hb[1], rout[tt]);
                }
            }
        } else {
            const int ci = p - 2;
            if (ci >= 0) {   // ci < NCHUNK guaranteed by p < NPHASE
                const float (*rin)[HID] = ring1[ci & 1];
#pragma unroll
                for (int tt = 0; tt < CH; ++tt) {
                    float a0 = bA, a1 = 0.f, g0 = bB, g1 = 0.f;
                    dot4<8>(reinterpret_cast<const float4*>(rin[tt]), wihA, wihB, a0, a1, g0, g1);
                    asm volatile("s_waitcnt lgkmcnt(0)" ::: "memory");
                    dot4<8>(reinterpret_cast<const float4*>(hb[2]), whhA, whhB, a0, a1, g0, g1);
                    gate_tail(l, a0 + a1, g0 + g1, c, hreg, hb[2], nullptr);
                }
            }
        }
        __syncthreads();
    }

    // final projection: last @ W_out.T + b_out  (wave2 holds h2[T-1])
    if (w == 2) {
        float s = (l < HID) ? hreg * wout : 0.0f;
#pragma unroll
        for (int off = 16; off; off >>= 1) s += __shfl_xor(s, off);
        if (l == 0) out[bi] = s + b_out[0];
    }
}

extern "C" void kernel_launch(void* const* d_in, const int* in_sizes, int n_in,
                              void* d_out, int out_size, void* d_ws, size_t ws_size,
                              hipStream_t stream) {
    const float* x      = (const float*)d_in[0];
    const float* W_ih0  = (const float*)d_in[1];
    const float* W_hh0  = (const float*)d_in[2];
    const float* b0     = (const float*)d_in[3];
    const float* W_ih1  = (const float*)d_in[4];
    const float* W_hh1  = (const float*)d_in[5];
    const float* b1     = (const float*)d_in[6];
    const float* W_ih2  = (const float*)d_in[7];
    const float* W_hh2  = (const float*)d_in[8];
    const float* b2     = (const float*)d_in[9];
    const float* W_out  = (const float*)d_in[10];
    const float* b_out  = (const float*)d_in[11];

    lstm3_pipe_kernel<<<256, 192, 0, stream>>>(x,
                                               W_ih0, W_hh0, b0,
                                               W_ih1, W_hh1, b1,
                                               W_ih2, W_hh2, b2,
                                               W_out, b_out,
                                               (float*)d_out);
}

// Round 4
// 699.801 us; speedup vs baseline: 5.8206x; 2.3991x over previous
//
#include <hip/hip_runtime.h>

// 3-layer LSTM, B=256, T=2048, H=32, in=64. fp32.
// ONE kernel: 256 blocks x 384 threads (6 waves), full wave specialization:
//   wave 3 (F0): xg0 = W_ih0 @ x + b0      (chunk p at phase p)
//   wave 0 (W0): layer-0 recurrence        (chunk p-1)
//   wave 4 (F1): xg1 = W_ih1 @ h0 + b1     (chunk p-2)
//   wave 1 (W1): layer-1 recurrence        (chunk p-3)
//   wave 5 (F2): xg2 = W_ih2 @ h1 + b2     (chunk p-4)
//   wave 2 (W2): layer-2 recurrence + proj (chunk p-5)
// Each wave's weights live branch-locally in VGPRs (no cross-wave liveness).
// All hand-offs via double-buffered LDS rings; one barrier per phase
// (divergent barrier sites, equal counts per wave). h_seq never hits HBM.

typedef float v2f __attribute__((ext_vector_type(2)));

constexpr int T_SEQ  = 2048;
constexpr int HID    = 32;
constexpr int CH     = 16;             // timesteps per chunk
constexpr int NCHUNK = T_SEQ / CH;     // 128
constexpr int NPHASE = NCHUNK + 5;     // pipeline depth 6

__device__ __forceinline__ float sigmoid_f(float x) { return 1.0f / (1.0f + __expf(-x)); }
__device__ __forceinline__ float tanh_f(float x)    { return 1.0f - 2.0f / (__expf(2.0f * x) + 1.0f); }

#define GLOAD_LDS16(gsrc, ldst)                                                              \
    __builtin_amdgcn_global_load_lds((const __attribute__((address_space(1))) void*)(gsrc), \
                                     (__attribute__((address_space(3))) void*)(ldst),        \
                                     16, 0, 0)
#define KEEPV(x) asm volatile("" : "+v"(x))

// feeder: xg[tt][l] = { b + W[row l] . in[tt],  b + W[row l+64] . in[tt] }
template<int N4>
__device__ __forceinline__ void feed_chunk(int l, const float* in, int stride,
                                           v2f (*xg)[64],
                                           const v2f (&wA)[N4 * 2], const v2f (&wB)[N4 * 2],
                                           float bAv, float bBv)
{
#pragma unroll
    for (int tt = 0; tt < CH; ++tt) {
        const float4* xt = reinterpret_cast<const float4*>(in + tt * stride);
        v2f aA = {bAv, 0.f}, aB = {bBv, 0.f};
#pragma unroll
        for (int i = 0; i < N4; ++i) {
            const float4 v = xt[i];
            const v2f lo = {v.x, v.y}, hi = {v.z, v.w};
            aA = lo * wA[2*i] + aA;  aA = hi * wA[2*i+1] + aA;
            aB = lo * wB[2*i] + aB;  aB = hi * wB[2*i+1] + aB;
        }
        v2f o; o.x = aA.x + aA.y; o.y = aB.x + aB.y;
        xg[tt][l] = o;                       // ds_write_b64
    }
}

// recurrent wave: one chunk of the LSTM recurrence.
// lane l<32: A=i, B=g(tanh); lane>=32: A=f, B=o. hbp = 32-float h broadcast.
__device__ __forceinline__ void recur_chunk(int l, const v2f (*xg)[64],
                                            float* hbp, float (*hr)[HID],
                                            const v2f (&wA)[16], const v2f (&wB)[16],
                                            float& c, float& hreg)
{
#pragma unroll
    for (int tt = 0; tt < CH; ++tt) {
        const v2f xgv = xg[tt][l];           // ds_read_b64 (own gate pair)
        // prev step's hbp write (and xgv) complete before hb reads below
        asm volatile("s_waitcnt lgkmcnt(0)" ::: "memory");
        const float4* h4 = reinterpret_cast<const float4*>(hbp);
        v2f aA = {xgv.x, 0.f}, aB = {xgv.y, 0.f};
#pragma unroll
        for (int i = 0; i < 8; ++i) {
            const float4 v = h4[i];
            const v2f lo = {v.x, v.y}, hi = {v.z, v.w};
            aA = lo * wA[2*i] + aA;  aA = hi * wA[2*i+1] + aA;
            aB = lo * wB[2*i] + aB;  aB = hi * wB[2*i+1] + aB;
        }
        const float ga = aA.x + aA.y, gb = aB.x + aB.y;
        const float sA = sigmoid_f(ga);
        const float tb = tanh_f(l < 32 ? gb : 0.5f * gb);
        const float vB = (l < 32) ? tb : fmaf(0.5f, tb, 0.5f);  // o via tanh half-arg
        const float fv = __shfl_xor(sA, 32);
        const float ov = __shfl_xor(vB, 32);
        const float cn = fmaf(fv, c, sA * vB);
        const float hn = ov * tanh_f(cn);
        if (l < HID) {
            c = cn; hreg = hn;
            hbp[l] = hn;                     // ds_write_b32 (next step's broadcast)
            if (hr) hr[tt][l] = hn;          // ring to next layer's feeder
        }
    }
}

__global__ __launch_bounds__(384, 2)
void lstm3_spec_kernel(const float* __restrict__ x,
                       const float* __restrict__ W_ih0, const float* __restrict__ W_hh0, const float* __restrict__ b0,
                       const float* __restrict__ W_ih1, const float* __restrict__ W_hh1, const float* __restrict__ b1,
                       const float* __restrict__ W_ih2, const float* __restrict__ W_hh2, const float* __restrict__ b2,
                       const float* __restrict__ W_out, const float* __restrict__ b_out,
                       float* __restrict__ out)
{
    const int bi = blockIdx.x;
    const int w  = threadIdx.x >> 6;
    const int l  = threadIdx.x & 63;

    __shared__ float xstage[CH * 64];        // 4 KB, F0 staging (single buffer)
    __shared__ v2f   xg0[2][CH][64];         // 16 KB each: gate pre-acts per layer
    __shared__ v2f   xg1[2][CH][64];
    __shared__ v2f   xg2[2][CH][64];
    __shared__ float h0r[2][CH][HID];        // 4 KB each: h chunk rings
    __shared__ float h1r[2][CH][HID];
    __shared__ float hb[3][HID];             // per-layer h broadcast

    if (w == 0) {                            // ---- layer-0 recurrence ----
        __builtin_amdgcn_s_setprio(1);
        v2f wA[16], wB[16];
        const v2f* pA = reinterpret_cast<const v2f*>(W_hh0 + l * 32);
        const v2f* pB = reinterpret_cast<const v2f*>(W_hh0 + (l + 64) * 32);
#pragma unroll
        for (int i = 0; i < 16; ++i) { wA[i] = pA[i]; KEEPV(wA[i]); wB[i] = pB[i]; KEEPV(wB[i]); }
        if (l < HID) hb[0][l] = 0.f;
        float c = 0.f, hreg = 0.f;
        __syncthreads();
        for (int p = 0; p < NPHASE; ++p) {
            const int ci = p - 1;
            if (ci >= 0 && ci < NCHUNK)
                recur_chunk(l, xg0[ci & 1], hb[0], h0r[ci & 1], wA, wB, c, hreg);
            __syncthreads();
        }
    } else if (w == 1) {                     // ---- layer-1 recurrence ----
        __builtin_amdgcn_s_setprio(1);
        v2f wA[16], wB[16];
        const v2f* pA = reinterpret_cast<const v2f*>(W_hh1 + l * 32);
        const v2f* pB = reinterpret_cast<const v2f*>(W_hh1 + (l + 64) * 32);
#pragma unroll
        for (int i = 0; i < 16; ++i) { wA[i] = pA[i]; KEEPV(wA[i]); wB[i] = pB[i]; KEEPV(wB[i]); }
        if (l < HID) hb[1][l] = 0.f;
        float c = 0.f, hreg = 0.f;
        __syncthreads();
        for (int p = 0; p < NPHASE; ++p) {
            const int ci = p - 3;
            if (ci >= 0 && ci < NCHUNK)
                recur_chunk(l, xg1[ci & 1], hb[1], h1r[ci & 1], wA, wB, c, hreg);
            __syncthreads();
        }
    } else if (w == 2) {                     // ---- layer-2 recurrence + projection ----
        __builtin_amdgcn_s_setprio(1);
        v2f wA[16], wB[16];
        const v2f* pA = reinterpret_cast<const v2f*>(W_hh2 + l * 32);
        const v2f* pB = reinterpret_cast<const v2f*>(W_hh2 + (l + 64) * 32);
#pragma unroll
        for (int i = 0; i < 16; ++i) { wA[i] = pA[i]; KEEPV(wA[i]); wB[i] = pB[i]; KEEPV(wB[i]); }
        const float woutv = (l < HID) ? W_out[l] : 0.f;
        if (l < HID) hb[2][l] = 0.f;
        float c = 0.f, hreg = 0.f;
        __syncthreads();
        for (int p = 0; p < NPHASE; ++p) {
            const int ci = p - 5;
            if (ci >= 0 && ci < NCHUNK)
                recur_chunk(l, xg2[ci & 1], hb[2], (float(*)[HID])nullptr, wA, wB, c, hreg);
            __syncthreads();
        }
        float s = (l < HID) ? hreg * woutv : 0.f;
#pragma unroll
        for (int off = 16; off; off >>= 1) s += __shfl_xor(s, off);
        if (l == 0) out[bi] = s + b_out[0];
    } else if (w == 3) {                     // ---- feeder L0: xg0 from x ----
        v2f wA[32], wB[32];
        const v2f* pA = reinterpret_cast<const v2f*>(W_ih0 + l * 64);
        const v2f* pB = reinterpret_cast<const v2f*>(W_ih0 + (l + 64) * 64);
#pragma unroll
        for (int i = 0; i < 32; ++i) { wA[i] = pA[i]; KEEPV(wA[i]); wB[i] = pB[i]; KEEPV(wB[i]); }
        const float bAv = b0[l], bBv = b0[l + 64];
        const float* src = x + (size_t)bi * T_SEQ * 64;
        __syncthreads();
        for (int p = 0; p < NPHASE; ++p) {
            if (p < NCHUNK) {
                const float* ns = src + (size_t)p * CH * 64;
#pragma unroll
                for (int i = 0; i < 4; ++i)
                    GLOAD_LDS16(ns + i * 256 + l * 4, &xstage[i * 256 + l * 4]);
                asm volatile("s_waitcnt vmcnt(0)" ::: "memory");
                feed_chunk<16>(l, xstage, 64, xg0[p & 1], wA, wB, bAv, bBv);
            }
            __syncthreads();
        }
    } else if (w == 4) {                     // ---- feeder L1: xg1 from h0 ring ----
        v2f wA[16], wB[16];
        const v2f* pA = reinterpret_cast<const v2f*>(W_ih1 + l * 32);
        const v2f* pB = reinterpret_cast<const v2f*>(W_ih1 + (l + 64) * 32);
#pragma unroll
        for (int i = 0; i < 16; ++i) { wA[i] = pA[i]; KEEPV(wA[i]); wB[i] = pB[i]; KEEPV(wB[i]); }
        const float bAv = b1[l], bBv = b1[l + 64];
        __syncthreads();
        for (int p = 0; p < NPHASE; ++p) {
            const int ci = p - 2;
            if (ci >= 0 && ci < NCHUNK)
                feed_chunk<8>(l, &h0r[ci & 1][0][0], HID, xg1[ci & 1], wA, wB, bAv, bBv);
            __syncthreads();
        }
    } else {                                 // ---- feeder L2: xg2 from h1 ring ----
        v2f wA[16], wB[16];
        const v2f* pA = reinterpret_cast<const v2f*>(W_ih2 + l * 32);
        const v2f* pB = reinterpret_cast<const v2f*>(W_ih2 + (l + 64) * 32);
#pragma unroll
        for (int i = 0; i < 16; ++i) { wA[i] = pA[i]; KEEPV(wA[i]); wB[i] = pB[i]; KEEPV(wB[i]); }
        const float bAv = b2[l], bBv = b2[l + 64];
        __syncthreads();
        for (int p = 0; p < NPHASE; ++p) {
            const int ci = p - 4;
            if (ci >= 0 && ci < NCHUNK)
                feed_chunk<8>(l, &h1r[ci & 1][0][0], HID, xg2[ci & 1], wA, wB, bAv, bBv);
            __syncthreads();
        }
    }
}

extern "C" void kernel_launch(void* const* d_in, const int* in_sizes, int n_in,
                              void* d_out, int out_size, void* d_ws, size_t ws_size,
                              hipStream_t stream) {
    const float* x      = (const float*)d_in[0];
    const float* W_ih0  = (const float*)d_in[1];
    const float* W_hh0  = (const float*)d_in[2];
    const float* b0     = (const float*)d_in[3];
    const float* W_ih1  = (const float*)d_in[4];
    const float* W_hh1  = (const float*)d_in[5];
    const float* b1     = (const float*)d_in[6];
    const float* W_ih2  = (const float*)d_in[7];
    const float* W_hh2  = (const float*)d_in[8];
    const float* b2     = (const float*)d_in[9];
    const float* W_out  = (const float*)d_in[10];
    const float* b_out  = (const float*)d_in[11];

    lstm3_spec_kernel<<<256, 384, 0, stream>>>(x,
                                               W_ih0, W_hh0, b0,
                                               W_ih1, W_hh1, b1,
                                               W_ih2, W_hh2, b2,
                                               W_out, b_out,
                                               (float*)d_out);
}